// Round 5
// baseline (102.033 us; speedup 1.0000x reference)
//
#include <hip/hip_runtime.h>
#include <hip/hip_fp16.h>

#define B_SZ    16384
#define NNZ_PER 32
#define F_DIM   768
#define H_DIM   512
#define SLICE_H 64                 // h per slice
#define NSLICE  8                  // 8 * 64 = 512
#define CHUNK   256                // positions per block
#define ROWB    80                 // LDS row stride (bytes): 16-aligned, spreads banks

typedef unsigned int  uint32;
typedef unsigned char uchar;

// ws layout (bytes)
#define WT8_OFF  0u                          // [NSLICE][F][64] e5m2 = 393216
#define PK_OFF   393216u                     // [B][64] uint32 = 4 MiB
#define PART_OFF (393216u + 4194304u)        // [NSLICE][B] f32 = 512 KiB

// ---------------------------------------------------------------------------
// fp32 -> e5m2 (RNE): e5m2 == top byte of fp16; decode (byte<<8) is exact fp16.
// ---------------------------------------------------------------------------
__device__ inline uchar f32_to_e5m2(float x) {
    __half h = __float2half_rn(x);
    unsigned short hb = *(unsigned short*)&h;
    unsigned short lsb = (hb >> 8) & 1;
    hb = (unsigned short)(hb + 0x7F + lsb);
    return (uchar)(hb >> 8);
}

// Prep 1: W_ft [H][F] fp32 -> Wt8 [slice][F][64] e5m2 (slice-major for
// contiguous 48 KB stage reads in the main kernel).
__global__ __launch_bounds__(256) void transpose_convert(
    const float* __restrict__ W, uchar* __restrict__ Wt8)
{
    __shared__ float tile[32][33];
    const int f0 = blockIdx.x * 32;
    const int h0 = blockIdx.y * 32;
    const int tx = threadIdx.x;
    const int ty = threadIdx.y;

#pragma unroll
    for (int i = 0; i < 32; i += 8)
        tile[ty + i][tx] = W[(h0 + ty + i) * F_DIM + f0 + tx];
    __syncthreads();
    const int s = h0 >> 6;                    // 32-tile lies in one 64-slice
#pragma unroll
    for (int i = 0; i < 32; i += 8) {
        const int f = f0 + ty + i;
        const int h = h0 + tx;
        Wt8[(size_t)s * (F_DIM * SLICE_H) + f * SLICE_H + (h & 63)] =
            f32_to_e5m2(tile[tx][ty + i]);
    }
}

// Prep 2: pack per-entry {f*80 (LDS row offset, fits 16 bits: 767*80=61360),
// v as fp16 in high half} for both stm (j<32) and nstm (j>=32).
__global__ __launch_bounds__(256) void pack_entries(
    const int*   __restrict__ stm_idx,
    const int*   __restrict__ nstm_idx,
    const float* __restrict__ stm_val,
    const float* __restrict__ nstm_val,
    uint32* __restrict__ packed)
{
    const int e = blockIdx.x * 256 + threadIdx.x;   // 0 .. B*64
    const int b = e >> 6, j = e & 63;
    const int NNZ = B_SZ * NNZ_PER;
    int f; float v;
    if (j < 32) { f = stm_idx [NNZ + b * 32 + j];        v = stm_val [b * 32 + j]; }
    else        { f = nstm_idx[NNZ + b * 32 + (j - 32)]; v = nstm_val[b * 32 + (j - 32)]; }
    __half hv = __float2half_rn(v);
    packed[e] = (uint32)(unsigned short)(f * ROWB) |
                ((uint32)(*(unsigned short*)&hv) << 16);
}

// ---------------------------------------------------------------------------
// Main: grid (64 chunks, 8 slices), 1024 threads (16 waves).
// Stage W slice [768][64] fp8 into LDS (row stride 80 B). Wave w handles 16
// positions in parallel: lane = p_local*4 + hs, hs*16 B = 16 h's per lane.
// Gather rows from LDS via ds_read_b128, decode e5m2->fp16 (perm), hfma2.
// Writes per-(slice,position) partial output dots; finalize kernel sums.
// ---------------------------------------------------------------------------
__global__ __launch_bounds__(1024, 4) void nnue_main(
    const uchar*  __restrict__ Wt8,
    const uint32* __restrict__ packed,
    const float*  __restrict__ b_ft,
    const float*  __restrict__ W_out,
    float* __restrict__ partials)
{
    __shared__ uchar Wl[F_DIM * ROWB];    // 61440 B
    const int tid   = threadIdx.x;
    const int chunk = blockIdx.x;
    const int s     = blockIdx.y;

    // Stage 48 KB slice -> LDS
    {
        const uchar* src = Wt8 + (size_t)s * (F_DIM * SLICE_H);
#pragma unroll
        for (int pass = 0; pass < 3; ++pass) {
            const int o = pass * 16384 + tid * 16;    // byte in slice
            const int f = o >> 6, col = o & 63;
            uint4 v = *(const uint4*)(src + o);
            *(uint4*)(&Wl[f * ROWB + col]) = v;
        }
    }
    __syncthreads();

    const int w    = tid >> 6;
    const int lane = tid & 63;
    const int hs   = lane & 3;           // 4 lanes x 16B cover the 64-h slice
    const int pl   = lane >> 2;          // 16 positions per wave
    const int pos  = chunk * CHUNK + w * 16 + pl;
    const int hb   = hs * 16;            // byte offset within LDS row

    const uint4* pk4 = (const uint4*)(packed + pos * 64);

    const uint32 selA = 0x01040004u;     // [0,b0,0,b1] -> half2
    const uint32 selB = 0x03040204u;     // [0,b2,0,b3] -> half2

    __half2 z = __float2half2_rn(0.f);
    __half2 sa[8] = {z,z,z,z,z,z,z,z};
    __half2 na[8] = {z,z,z,z,z,z,z,z};

#define PROC1(acc, e)                                                         \
    {                                                                         \
        const uint32 off = (e & 0xFFFFu) + (uint32)hb;                        \
        uint32 vvb = __builtin_amdgcn_perm(e, e, 0x03020302u);                \
        __half2 vv = *(__half2*)&vvb;                                         \
        uint4 wv = *(const uint4*)(&Wl[off]);                                 \
        uint32 p;                                                             \
        p = __builtin_amdgcn_perm(0u, wv.x, selA); acc[0] = __hfma2(*(__half2*)&p, vv, acc[0]); \
        p = __builtin_amdgcn_perm(0u, wv.x, selB); acc[1] = __hfma2(*(__half2*)&p, vv, acc[1]); \
        p = __builtin_amdgcn_perm(0u, wv.y, selA); acc[2] = __hfma2(*(__half2*)&p, vv, acc[2]); \
        p = __builtin_amdgcn_perm(0u, wv.y, selB); acc[3] = __hfma2(*(__half2*)&p, vv, acc[3]); \
        p = __builtin_amdgcn_perm(0u, wv.z, selA); acc[4] = __hfma2(*(__half2*)&p, vv, acc[4]); \
        p = __builtin_amdgcn_perm(0u, wv.z, selB); acc[5] = __hfma2(*(__half2*)&p, vv, acc[5]); \
        p = __builtin_amdgcn_perm(0u, wv.w, selA); acc[6] = __hfma2(*(__half2*)&p, vv, acc[6]); \
        p = __builtin_amdgcn_perm(0u, wv.w, selB); acc[7] = __hfma2(*(__half2*)&p, vv, acc[7]); \
    }

    uint4 pc = pk4[0];
#pragma unroll
    for (int jg = 0; jg < 8; ++jg) {          // stm entries 0..31
        uint4 cur = pc;
        pc = pk4[jg + 1];                     // jg+1 <= 8: first nstm group
        PROC1(sa, cur.x); PROC1(sa, cur.y); PROC1(sa, cur.z); PROC1(sa, cur.w);
    }
#pragma unroll
    for (int jg = 8; jg < 16; ++jg) {         // nstm entries 32..63
        uint4 cur = pc;
        if (jg < 15) pc = pk4[jg + 1];
        PROC1(na, cur.x); PROC1(na, cur.y); PROC1(na, cur.z); PROC1(na, cur.w);
    }
#undef PROC1

    // Epilogue: lane fully owns its 16 h's -> bias, clip, output-dot partial.
    const int h0 = s * SLICE_H + hb;
    float dot = 0.f;
#pragma unroll
    for (int i = 0; i < 8; ++i) {
        float2 bi  = *(const float2*)(b_ft  + h0 + 2 * i);
        float2 wsv = *(const float2*)(W_out + h0 + 2 * i);
        float2 wnv = *(const float2*)(W_out + H_DIM + h0 + 2 * i);
        float a0 = fminf(fmaxf(__low2float (sa[i]) + bi.x, 0.f), 1.f);
        float a1 = fminf(fmaxf(__high2float(sa[i]) + bi.y, 0.f), 1.f);
        float c0 = fminf(fmaxf(__low2float (na[i]) + bi.x, 0.f), 1.f);
        float c1 = fminf(fmaxf(__high2float(na[i]) + bi.y, 0.f), 1.f);
        dot += a0 * wsv.x + a1 * wsv.y + c0 * wnv.x + c1 * wnv.y;
    }
    dot += __shfl_xor(dot, 1, 64);
    dot += __shfl_xor(dot, 2, 64);
    if (hs == 0) partials[s * B_SZ + pos] = dot;
}

// Finalize: sum 8 slice partials, add b_out, sigmoid.
__global__ __launch_bounds__(256) void finalize(
    const float* __restrict__ partials,
    const float* __restrict__ b_out,
    float* __restrict__ out)
{
    const int b = blockIdx.x * 256 + threadIdx.x;
    float a = b_out[0];
#pragma unroll
    for (int s = 0; s < NSLICE; ++s)
        a += partials[s * B_SZ + b];
    out[b] = 1.f / (1.f + expf(-a));
}

extern "C" void kernel_launch(void* const* d_in, const int* in_sizes, int n_in,
                              void* d_out, int out_size, void* d_ws, size_t ws_size,
                              hipStream_t stream) {
    const int*   stm_idx  = (const int*)  d_in[0];
    const int*   nstm_idx = (const int*)  d_in[1];
    const float* stm_val  = (const float*)d_in[2];
    const float* nstm_val = (const float*)d_in[3];
    const float* W_ft     = (const float*)d_in[5];
    const float* b_ft     = (const float*)d_in[6];
    const float* W_out    = (const float*)d_in[7];
    const float* b_out    = (const float*)d_in[8];
    float*       out      = (float*)d_out;

    uchar*  Wt8      = (uchar*) ((char*)d_ws + WT8_OFF);
    uint32* packed   = (uint32*)((char*)d_ws + PK_OFF);
    float*  partials = (float*) ((char*)d_ws + PART_OFF);

    dim3 tb(32, 8);
    dim3 tg(F_DIM / 32, H_DIM / 32);
    transpose_convert<<<tg, tb, 0, stream>>>(W_ft, Wt8);

    pack_entries<<<(B_SZ * 64) / 256, 256, 0, stream>>>(
        stm_idx, nstm_idx, stm_val, nstm_val, packed);

    dim3 grid(B_SZ / CHUNK, NSLICE);          // 64 x 8 = 512 blocks
    nnue_main<<<grid, 1024, 0, stream>>>(Wt8, packed, b_ft, W_out, partials);

    finalize<<<B_SZ / 256, 256, 0, stream>>>(partials, b_out, out);
}